// Round 17
// baseline (159.155 us; speedup 1.0000x reference)
//
#include <hip/hip_runtime.h>
#include <hip/hip_bf16.h>

typedef __attribute__((ext_vector_type(8))) short short8;
typedef __attribute__((ext_vector_type(4))) short s16x4;
typedef __attribute__((ext_vector_type(4))) float f32x4;

#define N_ATOMS 100000
#define N_EDGES 800000
#define N_TILES (N_EDGES/16)      // 50000 tiles of 16 edges
#define N_CHUNKS ((N_ATOMS + 255) / 256)   // 391 scan chunks

// edge_msg geometry: R10/R16 EXACT (best measured: 67-71us steady).
// 768 blocks (3/CU resident) * 4 waves = 3072 waves, bounds (256,3) -> 84 VGPR.
// Occupancy levers exhausted (R8/R13/R14/R15 postmortems). R17: +setprio only.
#define MSG_BLOCKS 768
#define MSG_WAVES  (MSG_BLOCKS*4)

// ---- ws layout (bytes) ----
#define WS_MSG     0ULL                      // bf16 msg [N_EDGES][32] = 51,200,000
#define WS_OFFS    51200000ULL               // int offsets [N_ATOMS+1]
#define WS_COUNTS  51600016ULL               // int counts [N_ATOMS]
#define WS_RANK    58400016ULL               // int rank [N_EDGES]
#define WS_PART    61600016ULL               // int partials [512]
#define WS_NEED    61602064ULL

__device__ __forceinline__ short f2bf(float x) {
    __hip_bfloat16 h = __float2bfloat16(x);
    return __builtin_bit_cast(short, h);
}
__device__ __forceinline__ float bf2f(short b) {
    unsigned u = ((unsigned)(unsigned short)b) << 16;
    return __builtin_bit_cast(float, u);
}

// ---------------- CSR build (2-dispatch scan) ----------------
__global__ __launch_bounds__(256) void rank_kernel(const int2* __restrict__ pair,
                                                   int* __restrict__ counts,
                                                   int* __restrict__ rank) {
    int e = blockIdx.x * 256 + threadIdx.x;
    if (e < N_EDGES) rank[e] = atomicAdd(&counts[pair[e].x], 1);
}

__global__ __launch_bounds__(256) void scan_part(const int* __restrict__ counts,
                                                 int* __restrict__ partials) {
    const int tid = threadIdx.x;
    const int i = blockIdx.x * 256 + tid;
    int v = (i < N_ATOMS) ? counts[i] : 0;
#pragma unroll
    for (int off = 1; off < 64; off <<= 1) v += __shfl_xor(v, off);
    __shared__ int ws4[4];
    const int lane = tid & 63, wv = tid >> 6;
    if (lane == 0) ws4[wv] = v;
    __syncthreads();
    if (tid == 0) partials[blockIdx.x] = ws4[0] + ws4[1] + ws4[2] + ws4[3];
}

// scan_final with scan_mid folded in (R16): each block reduces partials[0..b) itself.
__global__ __launch_bounds__(256) void scan_final(const int* __restrict__ counts,
                                                  const int* __restrict__ partials,
                                                  int* __restrict__ offsets) {
    const int b   = blockIdx.x;
    const int tid = threadIdx.x;
    const int i   = b * 256 + tid;
    const int lane = tid & 63, wv = tid >> 6;
    __shared__ int ws4[4];
    __shared__ int sbase;

    if (wv == 0) {
        int acc = 0;
#pragma unroll
        for (int c = 0; c < 7; ++c) {                 // 7*64 = 448 >= N_CHUNKS
            const int idx = c * 64 + lane;
            acc += (idx < b) ? partials[idx] : 0;
        }
#pragma unroll
        for (int off = 1; off < 64; off <<= 1) acc += __shfl_xor(acc, off);
        if (lane == 0) sbase = acc;
    }

    int c = (i < N_ATOMS) ? counts[i] : 0;
    int inc = c;
#pragma unroll
    for (int off = 1; off < 64; off <<= 1) {
        int u = __shfl_up(inc, off);
        if (lane >= off) inc += u;
    }
    if (lane == 63) ws4[wv] = inc;
    __syncthreads();
    int base = sbase;
#pragma unroll
    for (int k = 0; k < 4; ++k) base += (k < wv) ? ws4[k] : 0;
    const int off = base + inc - c;                   // exclusive prefix
    if (i < N_ATOMS) offsets[i] = off;
    if (i == N_ATOMS - 1) offsets[N_ATOMS] = off + c;
}

// ---------------- phase A: per-edge messages via MFMA (R16 body + setprio) ----------------
// One wave per 16-edge tile computes all 32 output rows. m=0 A-frags in regs;
// m=1 + bias frags re-read from resident klds per body (anti-LICM pin).
// Pipeline: pair/rank/bond dist-2; offsets + atom-gather dist-1; bond LDS bounce.
// R17: s_setprio(1) around the MFMA cluster (T5; independent waves = attn-like regime).
__global__ __launch_bounds__(256, 3)
void edge_msg_kernel(const float* __restrict__ atom,
                     const float* __restrict__ bond,
                     const float* __restrict__ kern,
                     const float* __restrict__ bias,
                     const int2*  __restrict__ pair,
                     const int*   __restrict__ rank,
                     const int*   __restrict__ offsets,
                     short*       __restrict__ msg)
{
    __shared__ __align__(16) short klds[17*2*512];   // 34816 B, resident
    __shared__ __align__(16) float blds[4*320];      // 5120 B bond bounce (80B/edge)

    const int tid = threadIdx.x;
    for (int x = tid; x < 17*2*512; x += 256) {
        const int t = x & 7;
        const int l = (x >> 3) & 63;
        const int m = (x >> 9) & 1;
        const int b = x >> 10;
        const int i = m*16 + (l & 15);
        const int j = ((l >> 4) << 3) + t;
        const float v = (b < 16) ? kern[b*1024 + i*32 + j] : bias[i*32 + j];
        klds[x] = f2bf(v);
    }
    __syncthreads();

    const int wave = tid >> 6;
    const int lane = tid & 63;
    const int er   = lane & 15;
    const int jg   = lane >> 4;
    const int pid  = blockIdx.x * 4 + wave;          // 0..3071

    short8 afr[16];                                  // m=0 half, ch 0..15
#pragma unroll
    for (int b = 0; b < 16; ++b)
        afr[b] = *(const short8*)&klds[b*1024 + lane*8];

    const int ibase = jg*4;

    // bond staging lane map: lane l covers edge (l>>2), 16B quarter (l&3)
    float* bw = &blds[wave*320 + (lane >> 2)*20 + (lane & 3)*4];
    const float* brd = &blds[wave*320 + er*20];

    const int last = N_TILES - 1;

    // ---- prologue ----
    const int t1p = min(pid + MSG_WAVES, last);
    int2  p0 = pair[pid*16 + er];
    int   r0 = rank[pid*16 + er];
    f32x4 bv0 = *(const f32x4*)(bond + pid*256 + lane*4);
    int2  p1 = pair[t1p*16 + er];
    int   r1 = rank[t1p*16 + er];
    f32x4 bv1 = *(const f32x4*)(bond + t1p*256 + lane*4);
    *(f32x4*)bw = bv0;
    int   o0 = offsets[p0.x];
    f32x4 n0 = *(const f32x4*)(atom + p0.y*32 + jg*8);
    f32x4 n1 = *(const f32x4*)(atom + p0.y*32 + jg*8 + 4);

    for (int t = pid; t < N_TILES; t += MSG_WAVES) {
        // opaque zero: pins the per-body klds frag reads inside the loop (anti-LICM)
        int koff = 0;
        asm volatile("" : "+v"(koff));

        // t+2 loads (consumed 2 bodies later)
        const int t2 = min(t + 2*MSG_WAVES, last);
        const int2  p2  = pair[t2*16 + er];
        const int   r2  = rank[t2*16 + er];
        const f32x4 bv2 = *(const f32x4*)(bond + t2*256 + lane*4);

        // gathers for t+1 (p1 arrived >= 1 body ago): atom rows + CSR base
        const int   o1  = offsets[p1.x];
        const f32x4 n0n = *(const f32x4*)(atom + p1.y*32 + jg*8);
        const f32x4 n1n = *(const f32x4*)(atom + p1.y*32 + jg*8 + 4);

        short8 bfrag;
        bfrag[0]=f2bf(n0[0]); bfrag[1]=f2bf(n0[1]);
        bfrag[2]=f2bf(n0[2]); bfrag[3]=f2bf(n0[3]);
        bfrag[4]=f2bf(n1[0]); bfrag[5]=f2bf(n1[1]);
        bfrag[6]=f2bf(n1[2]); bfrag[7]=f2bf(n1[3]);

        f32x4 macc0 = {0.f,0.f,0.f,0.f};
        f32x4 macc1 = {0.f,0.f,0.f,0.f};
        const f32x4 z = {0.f,0.f,0.f,0.f};

        __builtin_amdgcn_s_setprio(1);
#pragma unroll
        for (int g = 0; g < 4; ++g) {
            const f32x4 q = *(const f32x4*)(brd + g*4);   // 4 bond coeffs (broadcast)
#pragma unroll
            for (int c = 0; c < 4; ++c) {
                const int b = g*4 + c;
                const short8 a1 = *(const short8*)&klds[b*1024 + 512 + lane*8 + koff];
                const f32x4 d0 = __builtin_amdgcn_mfma_f32_16x16x32_bf16(afr[b], bfrag, z, 0, 0, 0);
                const f32x4 d1 = __builtin_amdgcn_mfma_f32_16x16x32_bf16(a1,     bfrag, z, 0, 0, 0);
                macc0[0] = fmaf(q[c], d0[0], macc0[0]);
                macc0[1] = fmaf(q[c], d0[1], macc0[1]);
                macc0[2] = fmaf(q[c], d0[2], macc0[2]);
                macc0[3] = fmaf(q[c], d0[3], macc0[3]);
                macc1[0] = fmaf(q[c], d1[0], macc1[0]);
                macc1[1] = fmaf(q[c], d1[1], macc1[1]);
                macc1[2] = fmaf(q[c], d1[2], macc1[2]);
                macc1[3] = fmaf(q[c], d1[3], macc1[3]);
            }
        }
        {   // bias channel (unit coefficient)
            const short8 ab0 = *(const short8*)&klds[16*1024 +       lane*8 + koff];
            const short8 ab1 = *(const short8*)&klds[16*1024 + 512 + lane*8 + koff];
            const f32x4 d0 = __builtin_amdgcn_mfma_f32_16x16x32_bf16(ab0, bfrag, z, 0, 0, 0);
            const f32x4 d1 = __builtin_amdgcn_mfma_f32_16x16x32_bf16(ab1, bfrag, z, 0, 0, 0);
            macc0[0] += d0[0]; macc0[1] += d0[1]; macc0[2] += d0[2]; macc0[3] += d0[3];
            macc1[0] += d1[0]; macc1[1] += d1[1]; macc1[2] += d1[2]; macc1[3] += d1[3];
        }
        __builtin_amdgcn_s_setprio(0);

        // stage bond for t+1 (DS in-order per wave: q reads above already issued)
        *(f32x4*)bw = bv1;

        // store both halves at CSR slot = offsets[src] + rank
        const int sl = o0 + r0;
        s16x4 mv0, mv1;
        mv0[0]=f2bf(macc0[0]); mv0[1]=f2bf(macc0[1]);
        mv0[2]=f2bf(macc0[2]); mv0[3]=f2bf(macc0[3]);
        mv1[0]=f2bf(macc1[0]); mv1[1]=f2bf(macc1[1]);
        mv1[2]=f2bf(macc1[2]); mv1[3]=f2bf(macc1[3]);
        *(s16x4*)&msg[sl*32 + ibase]      = mv0;
        *(s16x4*)&msg[sl*32 + 16 + ibase] = mv1;

        // rotate pipeline state
        p0 = p1; p1 = p2; r0 = r1; r1 = r2; o0 = o1; bv1 = bv2;
        n0 = n0n; n1 = n1n;
    }
}

// ---------------- phase B: per-atom gather-sum (atomic-free, 2x unroll) ----------------
__global__ __launch_bounds__(256) void gather_kernel(const short* __restrict__ msg,
                                                     const int* __restrict__ offsets,
                                                     float* __restrict__ out) {
    const int tid = threadIdx.x;
    const int a = blockIdx.x * 32 + (tid >> 3);
    const int sub = (tid & 7) * 4;
    if (a >= N_ATOMS) return;
    const int b0 = offsets[a], b1 = offsets[a + 1];
    f32x4 acc0 = {0.f, 0.f, 0.f, 0.f};
    f32x4 acc1 = {0.f, 0.f, 0.f, 0.f};
    int k = b0;
    for (; k + 1 < b1; k += 2) {
        s16x4 mv0 = *(const s16x4*)&msg[k*32 + sub];
        s16x4 mv1 = *(const s16x4*)&msg[(k+1)*32 + sub];
        acc0[0] += bf2f(mv0[0]); acc0[1] += bf2f(mv0[1]);
        acc0[2] += bf2f(mv0[2]); acc0[3] += bf2f(mv0[3]);
        acc1[0] += bf2f(mv1[0]); acc1[1] += bf2f(mv1[1]);
        acc1[2] += bf2f(mv1[2]); acc1[3] += bf2f(mv1[3]);
    }
    if (k < b1) {
        s16x4 mv0 = *(const s16x4*)&msg[k*32 + sub];
        acc0[0] += bf2f(mv0[0]); acc0[1] += bf2f(mv0[1]);
        acc0[2] += bf2f(mv0[2]); acc0[3] += bf2f(mv0[3]);
    }
    acc0[0] += acc1[0]; acc0[1] += acc1[1]; acc0[2] += acc1[2]; acc0[3] += acc1[3];
    *(f32x4*)&out[a*32 + sub] = acc0;
}

// ---------------- fallback (R1 atomic version, known-passing) ----------------
__global__ __launch_bounds__(256) void zero_out(f32x4* __restrict__ out) {
    int i = blockIdx.x * 256 + threadIdx.x;
    f32x4 z = {0.f, 0.f, 0.f, 0.f};
    out[i] = z;
}

__global__ __launch_bounds__(256, 4)
void edge_kernel_atomic(const float* __restrict__ atom, const float* __restrict__ bond,
                        const int2* __restrict__ pair, const float* __restrict__ kern,
                        const float* __restrict__ bias, float* __restrict__ out)
{
    __shared__ __align__(16) short alds[17*2*512];
    const int tid = threadIdx.x;
    for (int x = tid; x < 17*2*512; x += 256) {
        const int t = x & 7;
        const int l = (x >> 3) & 63;
        const int m = (x >> 9) & 1;
        const int b = x >> 10;
        const int i = m*16 + (l & 15);
        const int j = ((l >> 4) << 3) + t;
        const float v = (b < 16) ? kern[b*1024 + i*32 + j] : bias[i*32 + j];
        alds[x] = f2bf(v);
    }
    __syncthreads();
    const int wave = tid >> 6, lane = tid & 63;
    const int er = lane & 15, jg = lane >> 4;
    const int wid = blockIdx.x * 4 + wave;
    const int m = wid & 1, pid = wid >> 1;
    short8 afr[17];
#pragma unroll
    for (int b = 0; b < 17; ++b)
        afr[b] = *(const short8*)&alds[(b*2 + m)*512 + lane*8];
    const int ibase = m*16 + jg*4;
    for (int tile = pid; tile < N_TILES; tile += 2048) {
        const int e = tile*16 + er;
        const int2 p = pair[e];
        const f32x4* arow = (const f32x4*)(atom + p.y * 32);
        const f32x4 n0 = arow[jg*2];
        const f32x4 n1 = arow[jg*2 + 1];
        short8 bfrag;
        bfrag[0] = f2bf(n0[0]); bfrag[1] = f2bf(n0[1]);
        bfrag[2] = f2bf(n0[2]); bfrag[3] = f2bf(n0[3]);
        bfrag[4] = f2bf(n1[0]); bfrag[5] = f2bf(n1[1]);
        bfrag[6] = f2bf(n1[2]); bfrag[7] = f2bf(n1[3]);
        const f32x4* brow = (const f32x4*)(bond + e * 16);
        const f32x4 q0 = brow[0], q1 = brow[1], q2 = brow[2], q3 = brow[3];
        float bb[17];
        bb[0]=q0[0];  bb[1]=q0[1];  bb[2]=q0[2];  bb[3]=q0[3];
        bb[4]=q1[0];  bb[5]=q1[1];  bb[6]=q1[2];  bb[7]=q1[3];
        bb[8]=q2[0];  bb[9]=q2[1];  bb[10]=q2[2]; bb[11]=q2[3];
        bb[12]=q3[0]; bb[13]=q3[1]; bb[14]=q3[2]; bb[15]=q3[3];
        bb[16]=1.0f;
        f32x4 macc = {0.f,0.f,0.f,0.f};
#pragma unroll
        for (int b = 0; b < 17; ++b) {
            f32x4 z = {0.f,0.f,0.f,0.f};
            f32x4 d = __builtin_amdgcn_mfma_f32_16x16x32_bf16(afr[b], bfrag, z, 0, 0, 0);
            macc[0] = fmaf(bb[b], d[0], macc[0]);
            macc[1] = fmaf(bb[b], d[1], macc[1]);
            macc[2] = fmaf(bb[b], d[2], macc[2]);
            macc[3] = fmaf(bb[b], d[3], macc[3]);
        }
        float* obase = out + p.x * 32 + ibase;
        atomicAdd(obase + 0, macc[0]);
        atomicAdd(obase + 1, macc[1]);
        atomicAdd(obase + 2, macc[2]);
        atomicAdd(obase + 3, macc[3]);
    }
}

extern "C" void kernel_launch(void* const* d_in, const int* in_sizes, int n_in,
                              void* d_out, int out_size, void* d_ws, size_t ws_size,
                              hipStream_t stream)
{
    (void)in_sizes; (void)n_in; (void)out_size;
    const float* atom = (const float*)d_in[0];
    const float* bond = (const float*)d_in[1];
    const int2*  pair = (const int2*)d_in[2];
    const float* kern = (const float*)d_in[3];
    const float* bias = (const float*)d_in[4];
    float* out = (float*)d_out;

    if (ws_size < WS_NEED) {
        zero_out<<<dim3(N_ATOMS*32/4/256), dim3(256), 0, stream>>>((f32x4*)out);
        edge_kernel_atomic<<<dim3(1024), dim3(256), 0, stream>>>(atom, bond, pair, kern, bias, out);
        return;
    }

    char* ws = (char*)d_ws;
    short* msg    = (short*)(ws + WS_MSG);
    int* offsets  = (int*)(ws + WS_OFFS);
    int* counts   = (int*)(ws + WS_COUNTS);
    int* rank     = (int*)(ws + WS_RANK);
    int* partials = (int*)(ws + WS_PART);

    const int eb = (N_EDGES + 255) / 256;          // 3125
    hipMemsetAsync(counts, 0, N_ATOMS * sizeof(int), stream);
    rank_kernel<<<dim3(eb), dim3(256), 0, stream>>>(pair, counts, rank);
    scan_part<<<dim3(N_CHUNKS), dim3(256), 0, stream>>>(counts, partials);
    scan_final<<<dim3(N_CHUNKS), dim3(256), 0, stream>>>(counts, partials, offsets);
    edge_msg_kernel<<<dim3(MSG_BLOCKS), dim3(256), 0, stream>>>(atom, bond, kern, bias, pair, rank, offsets, msg);
    gather_kernel<<<dim3((N_ATOMS + 31)/32), dim3(256), 0, stream>>>(msg, offsets, out);
}

// Round 18
// 107.664 us; speedup vs baseline: 1.4783x; 1.4783x over previous
//
#include <hip/hip_runtime.h>
#include <hip/hip_bf16.h>

typedef __attribute__((ext_vector_type(8))) short short8;
typedef __attribute__((ext_vector_type(4))) short s16x4;
typedef __attribute__((ext_vector_type(4))) float f32x4;

#define N_ATOMS 100000
#define N_EDGES 800000
#define N_TILES (N_EDGES/16)      // 50000 tiles of 16 edges
#define N_CHUNKS ((N_ATOMS + 255) / 256)   // 391 scan chunks

// edge_msg geometry: R10/R16 EXACT (best measured: 67-71us steady, 108.5 total).
// 768 blocks (3/CU resident) * 4 waves = 3072 waves, bounds (256,3) -> 84 VGPR.
// Levers exhausted (all counter-documented): bounds(256,4)->VGPR64 kills pipeline
// (R8); 512-thr->VGPR48 (R13); grid1024 -> 4th block not resident (R14); lookback
// scan serial chain +14us (R15); setprio -> prefetch starvation, FETCH 78->266MB
// (R17); 32x32 MFMA shape (R11), bf16 gather table (R12), shfl broadcast (R6),
// cooperative grid.sync ~90us/sync (R9) all regressed.
#define MSG_BLOCKS 768
#define MSG_WAVES  (MSG_BLOCKS*4)

// ---- ws layout (bytes) ----
#define WS_MSG     0ULL                      // bf16 msg [N_EDGES][32] = 51,200,000
#define WS_OFFS    51200000ULL               // int offsets [N_ATOMS+1]
#define WS_COUNTS  51600016ULL               // int counts [N_ATOMS]
#define WS_RANK    58400016ULL               // int rank [N_EDGES]
#define WS_PART    61600016ULL               // int partials [512]
#define WS_NEED    61602064ULL

__device__ __forceinline__ short f2bf(float x) {
    __hip_bfloat16 h = __float2bfloat16(x);
    return __builtin_bit_cast(short, h);
}
__device__ __forceinline__ float bf2f(short b) {
    unsigned u = ((unsigned)(unsigned short)b) << 16;
    return __builtin_bit_cast(float, u);
}

// ---------------- CSR build (2-dispatch scan) ----------------
__global__ __launch_bounds__(256) void rank_kernel(const int2* __restrict__ pair,
                                                   int* __restrict__ counts,
                                                   int* __restrict__ rank) {
    int e = blockIdx.x * 256 + threadIdx.x;
    if (e < N_EDGES) rank[e] = atomicAdd(&counts[pair[e].x], 1);
}

__global__ __launch_bounds__(256) void scan_part(const int* __restrict__ counts,
                                                 int* __restrict__ partials) {
    const int tid = threadIdx.x;
    const int i = blockIdx.x * 256 + tid;
    int v = (i < N_ATOMS) ? counts[i] : 0;
#pragma unroll
    for (int off = 1; off < 64; off <<= 1) v += __shfl_xor(v, off);
    __shared__ int ws4[4];
    const int lane = tid & 63, wv = tid >> 6;
    if (lane == 0) ws4[wv] = v;
    __syncthreads();
    if (tid == 0) partials[blockIdx.x] = ws4[0] + ws4[1] + ws4[2] + ws4[3];
}

// scan_final with scan_mid folded in (R16): each block reduces partials[0..b) itself.
__global__ __launch_bounds__(256) void scan_final(const int* __restrict__ counts,
                                                  const int* __restrict__ partials,
                                                  int* __restrict__ offsets) {
    const int b   = blockIdx.x;
    const int tid = threadIdx.x;
    const int i   = b * 256 + tid;
    const int lane = tid & 63, wv = tid >> 6;
    __shared__ int ws4[4];
    __shared__ int sbase;

    if (wv == 0) {
        int acc = 0;
#pragma unroll
        for (int c = 0; c < 7; ++c) {                 // 7*64 = 448 >= N_CHUNKS
            const int idx = c * 64 + lane;
            acc += (idx < b) ? partials[idx] : 0;
        }
#pragma unroll
        for (int off = 1; off < 64; off <<= 1) acc += __shfl_xor(acc, off);
        if (lane == 0) sbase = acc;
    }

    int c = (i < N_ATOMS) ? counts[i] : 0;
    int inc = c;
#pragma unroll
    for (int off = 1; off < 64; off <<= 1) {
        int u = __shfl_up(inc, off);
        if (lane >= off) inc += u;
    }
    if (lane == 63) ws4[wv] = inc;
    __syncthreads();
    int base = sbase;
#pragma unroll
    for (int k = 0; k < 4; ++k) base += (k < wv) ? ws4[k] : 0;
    const int off = base + inc - c;                   // exclusive prefix
    if (i < N_ATOMS) offsets[i] = off;
    if (i == N_ATOMS - 1) offsets[N_ATOMS] = off + c;
}

// ---------------- phase A: per-edge messages via MFMA (merged halves, R16 body EXACT) ----------------
// One wave per 16-edge tile computes all 32 output rows. m=0 A-frags in regs;
// m=1 + bias frags re-read from resident klds per body (anti-LICM pin).
// Pipeline: pair/rank/bond dist-2; offsets + atom-gather dist-1; bond LDS bounce.
__global__ __launch_bounds__(256, 3)
void edge_msg_kernel(const float* __restrict__ atom,
                     const float* __restrict__ bond,
                     const float* __restrict__ kern,
                     const float* __restrict__ bias,
                     const int2*  __restrict__ pair,
                     const int*   __restrict__ rank,
                     const int*   __restrict__ offsets,
                     short*       __restrict__ msg)
{
    __shared__ __align__(16) short klds[17*2*512];   // 34816 B, resident
    __shared__ __align__(16) float blds[4*320];      // 5120 B bond bounce (80B/edge)

    const int tid = threadIdx.x;
    for (int x = tid; x < 17*2*512; x += 256) {
        const int t = x & 7;
        const int l = (x >> 3) & 63;
        const int m = (x >> 9) & 1;
        const int b = x >> 10;
        const int i = m*16 + (l & 15);
        const int j = ((l >> 4) << 3) + t;
        const float v = (b < 16) ? kern[b*1024 + i*32 + j] : bias[i*32 + j];
        klds[x] = f2bf(v);
    }
    __syncthreads();

    const int wave = tid >> 6;
    const int lane = tid & 63;
    const int er   = lane & 15;
    const int jg   = lane >> 4;
    const int pid  = blockIdx.x * 4 + wave;          // 0..3071

    short8 afr[16];                                  // m=0 half, ch 0..15
#pragma unroll
    for (int b = 0; b < 16; ++b)
        afr[b] = *(const short8*)&klds[b*1024 + lane*8];

    const int ibase = jg*4;

    // bond staging lane map: lane l covers edge (l>>2), 16B quarter (l&3)
    float* bw = &blds[wave*320 + (lane >> 2)*20 + (lane & 3)*4];
    const float* brd = &blds[wave*320 + er*20];

    const int last = N_TILES - 1;

    // ---- prologue ----
    const int t1p = min(pid + MSG_WAVES, last);
    int2  p0 = pair[pid*16 + er];
    int   r0 = rank[pid*16 + er];
    f32x4 bv0 = *(const f32x4*)(bond + pid*256 + lane*4);
    int2  p1 = pair[t1p*16 + er];
    int   r1 = rank[t1p*16 + er];
    f32x4 bv1 = *(const f32x4*)(bond + t1p*256 + lane*4);
    *(f32x4*)bw = bv0;
    int   o0 = offsets[p0.x];
    f32x4 n0 = *(const f32x4*)(atom + p0.y*32 + jg*8);
    f32x4 n1 = *(const f32x4*)(atom + p0.y*32 + jg*8 + 4);

    for (int t = pid; t < N_TILES; t += MSG_WAVES) {
        // opaque zero: pins the per-body klds frag reads inside the loop (anti-LICM)
        int koff = 0;
        asm volatile("" : "+v"(koff));

        // t+2 loads (consumed 2 bodies later)
        const int t2 = min(t + 2*MSG_WAVES, last);
        const int2  p2  = pair[t2*16 + er];
        const int   r2  = rank[t2*16 + er];
        const f32x4 bv2 = *(const f32x4*)(bond + t2*256 + lane*4);

        // gathers for t+1 (p1 arrived >= 1 body ago): atom rows + CSR base
        const int   o1  = offsets[p1.x];
        const f32x4 n0n = *(const f32x4*)(atom + p1.y*32 + jg*8);
        const f32x4 n1n = *(const f32x4*)(atom + p1.y*32 + jg*8 + 4);

        short8 bfrag;
        bfrag[0]=f2bf(n0[0]); bfrag[1]=f2bf(n0[1]);
        bfrag[2]=f2bf(n0[2]); bfrag[3]=f2bf(n0[3]);
        bfrag[4]=f2bf(n1[0]); bfrag[5]=f2bf(n1[1]);
        bfrag[6]=f2bf(n1[2]); bfrag[7]=f2bf(n1[3]);

        f32x4 macc0 = {0.f,0.f,0.f,0.f};
        f32x4 macc1 = {0.f,0.f,0.f,0.f};
        const f32x4 z = {0.f,0.f,0.f,0.f};

#pragma unroll
        for (int g = 0; g < 4; ++g) {
            const f32x4 q = *(const f32x4*)(brd + g*4);   // 4 bond coeffs (broadcast)
#pragma unroll
            for (int c = 0; c < 4; ++c) {
                const int b = g*4 + c;
                const short8 a1 = *(const short8*)&klds[b*1024 + 512 + lane*8 + koff];
                const f32x4 d0 = __builtin_amdgcn_mfma_f32_16x16x32_bf16(afr[b], bfrag, z, 0, 0, 0);
                const f32x4 d1 = __builtin_amdgcn_mfma_f32_16x16x32_bf16(a1,     bfrag, z, 0, 0, 0);
                macc0[0] = fmaf(q[c], d0[0], macc0[0]);
                macc0[1] = fmaf(q[c], d0[1], macc0[1]);
                macc0[2] = fmaf(q[c], d0[2], macc0[2]);
                macc0[3] = fmaf(q[c], d0[3], macc0[3]);
                macc1[0] = fmaf(q[c], d1[0], macc1[0]);
                macc1[1] = fmaf(q[c], d1[1], macc1[1]);
                macc1[2] = fmaf(q[c], d1[2], macc1[2]);
                macc1[3] = fmaf(q[c], d1[3], macc1[3]);
            }
        }
        {   // bias channel (unit coefficient)
            const short8 ab0 = *(const short8*)&klds[16*1024 +       lane*8 + koff];
            const short8 ab1 = *(const short8*)&klds[16*1024 + 512 + lane*8 + koff];
            const f32x4 d0 = __builtin_amdgcn_mfma_f32_16x16x32_bf16(ab0, bfrag, z, 0, 0, 0);
            const f32x4 d1 = __builtin_amdgcn_mfma_f32_16x16x32_bf16(ab1, bfrag, z, 0, 0, 0);
            macc0[0] += d0[0]; macc0[1] += d0[1]; macc0[2] += d0[2]; macc0[3] += d0[3];
            macc1[0] += d1[0]; macc1[1] += d1[1]; macc1[2] += d1[2]; macc1[3] += d1[3];
        }

        // stage bond for t+1 (DS in-order per wave: q reads above already issued)
        *(f32x4*)bw = bv1;

        // store both halves at CSR slot = offsets[src] + rank
        const int sl = o0 + r0;
        s16x4 mv0, mv1;
        mv0[0]=f2bf(macc0[0]); mv0[1]=f2bf(macc0[1]);
        mv0[2]=f2bf(macc0[2]); mv0[3]=f2bf(macc0[3]);
        mv1[0]=f2bf(macc1[0]); mv1[1]=f2bf(macc1[1]);
        mv1[2]=f2bf(macc1[2]); mv1[3]=f2bf(macc1[3]);
        *(s16x4*)&msg[sl*32 + ibase]      = mv0;
        *(s16x4*)&msg[sl*32 + 16 + ibase] = mv1;

        // rotate pipeline state
        p0 = p1; p1 = p2; r0 = r1; r1 = r2; o0 = o1; bv1 = bv2;
        n0 = n0n; n1 = n1n;
    }
}

// ---------------- phase B: per-atom gather-sum (atomic-free, 2x unroll) ----------------
__global__ __launch_bounds__(256) void gather_kernel(const short* __restrict__ msg,
                                                     const int* __restrict__ offsets,
                                                     float* __restrict__ out) {
    const int tid = threadIdx.x;
    const int a = blockIdx.x * 32 + (tid >> 3);
    const int sub = (tid & 7) * 4;
    if (a >= N_ATOMS) return;
    const int b0 = offsets[a], b1 = offsets[a + 1];
    f32x4 acc0 = {0.f, 0.f, 0.f, 0.f};
    f32x4 acc1 = {0.f, 0.f, 0.f, 0.f};
    int k = b0;
    for (; k + 1 < b1; k += 2) {
        s16x4 mv0 = *(const s16x4*)&msg[k*32 + sub];
        s16x4 mv1 = *(const s16x4*)&msg[(k+1)*32 + sub];
        acc0[0] += bf2f(mv0[0]); acc0[1] += bf2f(mv0[1]);
        acc0[2] += bf2f(mv0[2]); acc0[3] += bf2f(mv0[3]);
        acc1[0] += bf2f(mv1[0]); acc1[1] += bf2f(mv1[1]);
        acc1[2] += bf2f(mv1[2]); acc1[3] += bf2f(mv1[3]);
    }
    if (k < b1) {
        s16x4 mv0 = *(const s16x4*)&msg[k*32 + sub];
        acc0[0] += bf2f(mv0[0]); acc0[1] += bf2f(mv0[1]);
        acc0[2] += bf2f(mv0[2]); acc0[3] += bf2f(mv0[3]);
    }
    acc0[0] += acc1[0]; acc0[1] += acc1[1]; acc0[2] += acc1[2]; acc0[3] += acc1[3];
    *(f32x4*)&out[a*32 + sub] = acc0;
}

// ---------------- fallback (R1 atomic version, known-passing) ----------------
__global__ __launch_bounds__(256) void zero_out(f32x4* __restrict__ out) {
    int i = blockIdx.x * 256 + threadIdx.x;
    f32x4 z = {0.f, 0.f, 0.f, 0.f};
    out[i] = z;
}

__global__ __launch_bounds__(256, 4)
void edge_kernel_atomic(const float* __restrict__ atom, const float* __restrict__ bond,
                        const int2* __restrict__ pair, const float* __restrict__ kern,
                        const float* __restrict__ bias, float* __restrict__ out)
{
    __shared__ __align__(16) short alds[17*2*512];
    const int tid = threadIdx.x;
    for (int x = tid; x < 17*2*512; x += 256) {
        const int t = x & 7;
        const int l = (x >> 3) & 63;
        const int m = (x >> 9) & 1;
        const int b = x >> 10;
        const int i = m*16 + (l & 15);
        const int j = ((l >> 4) << 3) + t;
        const float v = (b < 16) ? kern[b*1024 + i*32 + j] : bias[i*32 + j];
        alds[x] = f2bf(v);
    }
    __syncthreads();
    const int wave = tid >> 6, lane = tid & 63;
    const int er = lane & 15, jg = lane >> 4;
    const int wid = blockIdx.x * 4 + wave;
    const int m = wid & 1, pid = wid >> 1;
    short8 afr[17];
#pragma unroll
    for (int b = 0; b < 17; ++b)
        afr[b] = *(const short8*)&alds[(b*2 + m)*512 + lane*8];
    const int ibase = m*16 + jg*4;
    for (int tile = pid; tile < N_TILES; tile += 2048) {
        const int e = tile*16 + er;
        const int2 p = pair[e];
        const f32x4* arow = (const f32x4*)(atom + p.y * 32);
        const f32x4 n0 = arow[jg*2];
        const f32x4 n1 = arow[jg*2 + 1];
        short8 bfrag;
        bfrag[0] = f2bf(n0[0]); bfrag[1] = f2bf(n0[1]);
        bfrag[2] = f2bf(n0[2]); bfrag[3] = f2bf(n0[3]);
        bfrag[4] = f2bf(n1[0]); bfrag[5] = f2bf(n1[1]);
        bfrag[6] = f2bf(n1[2]); bfrag[7] = f2bf(n1[3]);
        const f32x4* brow = (const f32x4*)(bond + e * 16);
        const f32x4 q0 = brow[0], q1 = brow[1], q2 = brow[2], q3 = brow[3];
        float bb[17];
        bb[0]=q0[0];  bb[1]=q0[1];  bb[2]=q0[2];  bb[3]=q0[3];
        bb[4]=q1[0];  bb[5]=q1[1];  bb[6]=q1[2];  bb[7]=q1[3];
        bb[8]=q2[0];  bb[9]=q2[1];  bb[10]=q2[2]; bb[11]=q2[3];
        bb[12]=q3[0]; bb[13]=q3[1]; bb[14]=q3[2]; bb[15]=q3[3];
        bb[16]=1.0f;
        f32x4 macc = {0.f,0.f,0.f,0.f};
#pragma unroll
        for (int b = 0; b < 17; ++b) {
            f32x4 z = {0.f,0.f,0.f,0.f};
            f32x4 d = __builtin_amdgcn_mfma_f32_16x16x32_bf16(afr[b], bfrag, z, 0, 0, 0);
            macc[0] = fmaf(bb[b], d[0], macc[0]);
            macc[1] = fmaf(bb[b], d[1], macc[1]);
            macc[2] = fmaf(bb[b], d[2], macc[2]);
            macc[3] = fmaf(bb[b], d[3], macc[3]);
        }
        float* obase = out + p.x * 32 + ibase;
        atomicAdd(obase + 0, macc[0]);
        atomicAdd(obase + 1, macc[1]);
        atomicAdd(obase + 2, macc[2]);
        atomicAdd(obase + 3, macc[3]);
    }
}

extern "C" void kernel_launch(void* const* d_in, const int* in_sizes, int n_in,
                              void* d_out, int out_size, void* d_ws, size_t ws_size,
                              hipStream_t stream)
{
    (void)in_sizes; (void)n_in; (void)out_size;
    const float* atom = (const float*)d_in[0];
    const float* bond = (const float*)d_in[1];
    const int2*  pair = (const int2*)d_in[2];
    const float* kern = (const float*)d_in[3];
    const float* bias = (const float*)d_in[4];
    float* out = (float*)d_out;

    if (ws_size < WS_NEED) {
        zero_out<<<dim3(N_ATOMS*32/4/256), dim3(256), 0, stream>>>((f32x4*)out);
        edge_kernel_atomic<<<dim3(1024), dim3(256), 0, stream>>>(atom, bond, pair, kern, bias, out);
        return;
    }

    char* ws = (char*)d_ws;
    short* msg    = (short*)(ws + WS_MSG);
    int* offsets  = (int*)(ws + WS_OFFS);
    int* counts   = (int*)(ws + WS_COUNTS);
    int* rank     = (int*)(ws + WS_RANK);
    int* partials = (int*)(ws + WS_PART);

    const int eb = (N_EDGES + 255) / 256;          // 3125
    hipMemsetAsync(counts, 0, N_ATOMS * sizeof(int), stream);
    rank_kernel<<<dim3(eb), dim3(256), 0, stream>>>(pair, counts, rank);
    scan_part<<<dim3(N_CHUNKS), dim3(256), 0, stream>>>(counts, partials);
    scan_final<<<dim3(N_CHUNKS), dim3(256), 0, stream>>>(counts, partials, offsets);
    edge_msg_kernel<<<dim3(MSG_BLOCKS), dim3(256), 0, stream>>>(atom, bond, kern, bias, pair, rank, offsets, msg);
    gather_kernel<<<dim3((N_ATOMS + 31)/32), dim3(256), 0, stream>>>(msg, offsets, out);
}